// Round 1
// 409.015 us; speedup vs baseline: 1.0726x; 1.0726x over previous
//
#include <hip/hip_runtime.h>
#include <hip/hip_bf16.h>
#include <cmath>

// ---------------------------------------------------------------------------
// BeliefTransformerBlock: LN1 -> QKV -> masked attention -> LN2 -> FC+GELU -> proj
// B=32, N=1024, D=512.  GEMMs: mfma_f32_16x16x32_f16, fp32 accumulate,
// global_load_lds(16B) staging, BK=64 K-loop, XOR-swizzled LDS.
//
// R1 changes vs previous best (438.7 us):
//  - T1 bijective XCD swizzle in gemm_bt for gridDim.z==1 launches (QKV/FC/proj):
//    same-A-stripe column blocks land on the SAME XCD -> A stripe L2-fill once
//    per chunk instead of 8x (FETCH_SIZE 136MB -> ~50MB predicted on QKV).
//  - Attention merged to ONE phase over all 32 batches (was 2 phases of 16):
//    scoresAll -> d_out[0:64MiB) (h dead), y -> ws+4MiB (qk dead after scores).
//    3 launches instead of 6, double-size grids, fewer tails.
//  - softmax_wave skips loads past round64(size) (~32MB less read traffic).
//
// d_ws layout (floor 100 MiB):
//   0  wqkvT/wfcT/wprojT (4 MiB)
//   4  qk [b][n][1024] q|k (64 MiB)   -> after scores: y @4 (32), ln2o @36 (32)
//   68 vT [b][d][n] (32 MiB)          -> after attnV: gelub @68 (32)
// d_out (64 MiB): h/scoresAll scratch, finally fp32 out.
// ---------------------------------------------------------------------------

using f16 = _Float16;
typedef _Float16 f16x8 __attribute__((ext_vector_type(8)));
typedef _Float16 f16x4 __attribute__((ext_vector_type(4)));
typedef _Float16 f16x2 __attribute__((ext_vector_type(2)));
typedef float f32x4 __attribute__((ext_vector_type(4)));

#define NB 32
#define NN 1024
#define ND 512

#define GLOAD_LDS16(g, l)                                                     \
    __builtin_amdgcn_global_load_lds(                                         \
        (const __attribute__((address_space(1))) void*)(g),                   \
        (__attribute__((address_space(3))) void*)(l), 16, 0, 0)

// ---------------------------------------------------------------------------
// All three weights cast + transposed in ONE launch. z: 0=qkv 1=fc 2=proj.
// ---------------------------------------------------------------------------
__global__ void transpose_cast_all(const float* __restrict__ wqkv, f16* __restrict__ wqkvT,
                                   const float* __restrict__ wfc, f16* __restrict__ wfcT,
                                   const float* __restrict__ wproj, f16* __restrict__ wprojT) {
    const int z = blockIdx.z;
    const float* w = (z == 0) ? wqkv : (z == 1) ? wfc : wproj;
    f16* wT       = (z == 0) ? wqkvT : (z == 1) ? wfcT : wprojT;
    const int Ncols = (z == 0) ? 1536 : 512;
    if ((int)blockIdx.x * 32 >= Ncols) return;

    __shared__ float tile[32][33];
    const int n0 = blockIdx.x * 32, k0 = blockIdx.y * 32;
    const int tx = threadIdx.x, ty = threadIdx.y;
    for (int i = ty; i < 32; i += 8)
        tile[i][tx] = w[(long long)(k0 + i) * Ncols + n0 + tx];
    __syncthreads();
    for (int i = ty; i < 32; i += 8)
        wT[(long long)(n0 + i) * 512 + k0 + tx] = (f16)tile[tx][i];
}

// ---------------------------------------------------------------------------
// LayerNorm over last dim (512), no bias. Output fp16. One block per row.
// ---------------------------------------------------------------------------
template <typename TIN>
__global__ __launch_bounds__(256) void ln_kernel(const TIN* __restrict__ x,
                                                 const float* __restrict__ gamma,
                                                 f16* __restrict__ out) {
    const int tid = threadIdx.x;
    const long long base = (long long)blockIdx.x * ND;
    float v0, v1;
    if constexpr (sizeof(TIN) == 4) {
        const float2 t = ((const float2*)(x + base))[tid];
        v0 = t.x; v1 = t.y;
    } else {
        const f16x2 t = ((const f16x2*)(x + base))[tid];
        v0 = (float)t.x; v1 = (float)t.y;
    }

    __shared__ float red[8];
    const int wave = tid >> 6, lane = tid & 63;

    float s = v0 + v1;
#pragma unroll
    for (int o = 32; o > 0; o >>= 1) s += __shfl_down(s, o, 64);
    if (lane == 0) red[wave] = s;
    __syncthreads();
    const float mean = (red[0] + red[1] + red[2] + red[3]) * (1.f / 512.f);
    __syncthreads();

    const float d0 = v0 - mean, d1 = v1 - mean;
    float q = d0 * d0 + d1 * d1;
#pragma unroll
    for (int o = 32; o > 0; o >>= 1) q += __shfl_down(q, o, 64);
    if (lane == 0) red[wave] = q;
    __syncthreads();
    const float var = (red[0] + red[1] + red[2] + red[3]) * (1.f / 512.f);
    const float rstd = rsqrtf(var + 1e-5f);

    f16x2 o2;
    o2.x = (f16)(d0 * rstd * gamma[2 * tid]);
    o2.y = (f16)(d1 * rstd * gamma[2 * tid + 1]);
    ((f16x2*)(out + base))[tid] = o2;
}

// ---------------------------------------------------------------------------
// Masked softmax, fp16 in-place, one WAVE per row (no LDS, no barriers).
// Loads AND stores only c < round64(sz) (attn@V's BK=64 K bound; zero tail).
// ---------------------------------------------------------------------------
__global__ __launch_bounds__(256) void softmax_wave(f16* __restrict__ scores,
                                                    const int* __restrict__ sizes) {
    const int b = blockIdx.y;
    const int wave = threadIdx.x >> 6, lane = threadIdx.x & 63;
    const int row = blockIdx.x * 4 + wave;
    f16* srow = scores + ((long long)b * NN + row) * NN;
    const int sz = sizes[b];
    const int keff = (sz + 63) & ~63;
    const int cbase = lane * 16;

    float v[16];
    if (cbase < keff) {
        const f16x8 a0 = *(const f16x8*)&srow[cbase];
        const f16x8 a1 = *(const f16x8*)&srow[cbase + 8];
#pragma unroll
        for (int e = 0; e < 8; e++) { v[e] = (float)a0[e]; v[8 + e] = (float)a1[e]; }
    } else {
#pragma unroll
        for (int e = 0; e < 16; e++) v[e] = 0.f;
    }

    float m = -1e30f;
#pragma unroll
    for (int e = 0; e < 16; e++)
        if (cbase + e < sz) m = fmaxf(m, v[e]);
#pragma unroll
    for (int o = 32; o > 0; o >>= 1) m = fmaxf(m, __shfl_xor(m, o, 64));

    float s = 0.f;
#pragma unroll
    for (int e = 0; e < 16; e++) {
        v[e] = (cbase + e < sz) ? __expf(v[e] - m) : 0.f;
        s += v[e];
    }
#pragma unroll
    for (int o = 32; o > 0; o >>= 1) s += __shfl_xor(s, o, 64);
    const float inv = 1.f / s;

    if (cbase < keff) {
        f16x8 o0, o1;
#pragma unroll
        for (int e = 0; e < 8; e++) {
            o0[e] = (f16)(v[e] * inv);
            o1[e] = (f16)(v[8 + e] * inv);
        }
        *(f16x8*)&srow[cbase] = o0;
        *(f16x8*)&srow[cbase + 8] = o1;
    }
}

// ---------------------------------------------------------------------------
// GEMM: C[M][N] = A[M][K] * Bt[N][K]^T.  128x128 tile, 4 waves, 4x4 MFMA
// 16x16x32_f16 per wave, BK=64 (8 barrier pairs for K=512 instead of 16).
// LDS granule swizzle g' = g ^ (row&7); glds dst stays wave-uniform tid*16.
// T1: bijective XCD swizzle when gridDim.z==1 (QKV/FC/proj): same-stripe
// column blocks -> same XCD -> A stripes L2-hit instead of 8x L2-fill.
// MODE 0: fp16*alpha. 1: fp32*alpha. 2: GELU fp16. 3: QKV split (qk + vT^T).
// MASKN: skip block if n0 >= sizes[z].  MASKK: K bounded at round64(sizes[z]).
// ---------------------------------------------------------------------------
__device__ __forceinline__ float gelu_exact(float x) {
    return 0.5f * x * (1.f + erff(x * 0.70710678118654752f));
}

template <int MODE, int MASKN, int MASKK>
__global__ __launch_bounds__(256) void gemm_bt(
    const f16* __restrict__ A, int lda, long long strideA,
    const f16* __restrict__ Bt, int ldb, long long strideB,
    void* __restrict__ Cv, int ldc, long long strideC,
    int K, float alpha, const int* __restrict__ sizes, void* __restrict__ Cv2) {
    __shared__ __align__(16) f16 As[128 * 64];
    __shared__ __align__(16) f16 Bs[128 * 64];

    const int tid = threadIdx.x;
    const int wave = tid >> 6, lane = tid & 63;
    const int wr = (wave >> 1) * 64, wc = (wave & 1) * 64;
    const int lrow = lane & 15, quad = lane >> 4;

    // T1 XCD swizzle (bijective, m204 form) for single-z launches
    int bx = blockIdx.x, by = blockIdx.y;
    if (gridDim.z == 1) {
        const int gx = gridDim.x;
        const int nwg = gx * (int)gridDim.y;
        const int id = by * gx + bx;
        const int q = nwg >> 3, r = nwg & 7;
        const int xcd = id & 7, slot = id >> 3;
        const int wid = (xcd < r) ? (xcd * (q + 1) + slot)
                                  : (r * (q + 1) + (xcd - r) * q + slot);
        bx = wid % gx;
        by = wid / gx;
    }
    const long long m0 = (long long)by * 128;
    const long long n0 = (long long)bx * 128;

    if (MASKN) {
        if (n0 >= sizes[blockIdx.z]) return;
    }
    int Keff = K;
    if (MASKK) {
        const int ke = (sizes[blockIdx.z] + 63) & ~63;
        if (ke < Keff) Keff = ke;
    }

    A += (long long)blockIdx.z * strideA;
    Bt += (long long)blockIdx.z * strideB;

    f32x4 acc[4][4];
#pragma unroll
    for (int i = 0; i < 4; i++)
#pragma unroll
        for (int j = 0; j < 4; j++) acc[i][j] = (f32x4){0.f, 0.f, 0.f, 0.f};

    // staging: 4 passes/matrix; slot s -> row=s>>3, granule g=s&7,
    // source granule gc = g ^ (row&7) (self-inverse swizzle)
    const f16* Ap[4];
    const f16* Bp[4];
#pragma unroll
    for (int p = 0; p < 4; p++) {
        const int s = tid + p * 256;
        const int r = s >> 3, c = ((s & 7) ^ (r & 7)) * 8;
        Ap[p] = A + (m0 + r) * lda + c;
        Bp[p] = Bt + (n0 + r) * ldb + c;
    }

    for (int k0 = 0; k0 < Keff; k0 += 64) {
        __syncthreads();
#pragma unroll
        for (int p = 0; p < 4; p++) GLOAD_LDS16(Ap[p] + k0, &As[(tid + p * 256) * 8]);
#pragma unroll
        for (int p = 0; p < 4; p++) GLOAD_LDS16(Bp[p] + k0, &Bs[(tid + p * 256) * 8]);
        __syncthreads();

#pragma unroll
        for (int h = 0; h < 2; h++) {
            const int gq = ((h * 4 + quad) ^ (lrow & 7)) * 8;
            f16x8 af[4], bf[4];
#pragma unroll
            for (int i = 0; i < 4; i++)
                af[i] = *(const f16x8*)&As[(wr + i * 16 + lrow) * 64 + gq];
#pragma unroll
            for (int j = 0; j < 4; j++)
                bf[j] = *(const f16x8*)&Bs[(wc + j * 16 + lrow) * 64 + gq];
#pragma unroll
            for (int i = 0; i < 4; i++)
#pragma unroll
                for (int j = 0; j < 4; j++)
                    acc[i][j] = __builtin_amdgcn_mfma_f32_16x16x32_f16(af[i], bf[j], acc[i][j], 0, 0, 0);
        }
    }

    // epilogue: C/D layout col=lane&15, row=quad*4+reg
    if (MODE == 3 && n0 >= 1024) {
        // V columns: store transposed into vT[b][d][n] as packed f16x4
        f16* vTp = (f16*)Cv2;
#pragma unroll
        for (int i = 0; i < 4; i++) {
            const long long rbase = m0 + wr + i * 16 + quad * 4;
            const long long bb = rbase >> 10;
            const long long nrow = rbase & 1023;
#pragma unroll
            for (int j = 0; j < 4; j++) {
                const long long col = n0 + wc + j * 16 + lrow - 1024;
                f16x4 pk;
#pragma unroll
                for (int r = 0; r < 4; r++) pk[r] = (f16)acc[i][j][r];
                *(f16x4*)&vTp[bb * ND * NN + col * NN + nrow] = pk;
            }
        }
        return;
    }
    float* Cf = (float*)Cv + (long long)blockIdx.z * strideC;
    f16* Ch = (f16*)Cv + (long long)blockIdx.z * strideC;
#pragma unroll
    for (int i = 0; i < 4; i++) {
        const long long rbase = m0 + wr + i * 16 + quad * 4;
#pragma unroll
        for (int j = 0; j < 4; j++) {
            const long long col = n0 + wc + j * 16 + lrow;
#pragma unroll
            for (int r = 0; r < 4; r++) {
                float vv = acc[i][j][r];
                if (MODE == 1) {
                    Cf[(rbase + r) * ldc + col] = vv * alpha;
                } else if (MODE == 2) {
                    Ch[(rbase + r) * ldc + col] = (f16)gelu_exact(vv);
                } else {
                    Ch[(rbase + r) * ldc + col] = (f16)(vv * alpha);
                }
            }
        }
    }
}

// ---------------------------------------------------------------------------
// Launch
// ---------------------------------------------------------------------------
extern "C" void kernel_launch(void* const* d_in, const int* in_sizes, int n_in,
                              void* d_out, int out_size, void* d_ws, size_t ws_size,
                              hipStream_t stream) {
    const float* x     = (const float*)d_in[0];
    const int*   sizes = (const int*)d_in[1];
    const float* g1    = (const float*)d_in[2];
    const float* wqkv  = (const float*)d_in[3];
    const float* g2    = (const float*)d_in[4];
    const float* wfc   = (const float*)d_in[5];
    const float* wproj = (const float*)d_in[6];
    float* out = (float*)d_out;
    char* ws = (char*)d_ws;

    // ---- d_ws layout (floor: 100 MiB, proven available) ----
    f16* wqkvT  = (f16*)(ws + (0ull << 20));    // 1.5 MiB  [1536][512]
    f16* wfcT   = (f16*)(ws + (2ull << 20));    // 0.5 MiB
    f16* wprojT = (f16*)(ws + (3ull << 20));    // 0.5 MiB
    f16* qk     = (f16*)(ws + (4ull << 20));    // 64 MiB [b][n][1024] (q|k)
    f16* vT     = (f16*)(ws + (68ull << 20));   // 32 MiB [b][d][n]
    f16* y      = (f16*)(ws + (4ull << 20));    // 32 MiB (qk lo, dead after scores)
    f16* ln2o   = (f16*)(ws + (36ull << 20));   // 32 MiB (qk hi, dead after scores)
    f16* gelub  = (f16*)(ws + (68ull << 20));   // 32 MiB (vT, dead after attnV)

    // ---- d_out scratch ----
    f16* h      = (f16*)d_out;   // 32 MiB, dead after QKV
    f16* scores = (f16*)d_out;   // 64 MiB (all 32 batches; h dead)

    const long long sstr = (long long)NN * NN;     // score batch stride
    const long long qstr = (long long)NN * 1024;   // qk batch stride
    const long long vstr = (long long)ND * NN;     // vT batch stride
    const long long ystr = (long long)NN * ND;     // y batch stride

    // weights -> fp16 transposed (one launch)
    transpose_cast_all<<<dim3(48, 16, 3), dim3(32, 8), 0, stream>>>(
        wqkv, wqkvT, wfc, wfcT, wproj, wprojT);

    // LN1: x -> h
    ln_kernel<float><<<NB * NN, 256, 0, stream>>>(x, g1, h);

    // QKV: q,k -> qk[b][n][1024]; v -> vT[b][d][n] (fused transpose)
    gemm_bt<3, 0, 0><<<dim3(12, 256, 1), 256, 0, stream>>>(
        h, 512, 0, wqkvT, 512, 0, qk, 1024, 0, 512, 1.0f, nullptr, vT);

    // ---- attention, single phase over all 32 batches ----
    // scores (fp16) = q @ k^T / sqrt(D); skip fully-masked column blocks
    gemm_bt<0, 1, 0><<<dim3(8, 8, 32), 256, 0, stream>>>(
        qk, 1024, qstr, qk + 512, 1024, qstr,
        scores, NN, sstr, 512, 0.044194173824159216f, sizes, nullptr);

    // masked softmax in place (wave per row), zero-fill to round64(sz)
    softmax_wave<<<dim3(NN / 4, NB), 256, 0, stream>>>(scores, sizes);

    // y = attn @ v; K bounded at round64(size)
    gemm_bt<0, 0, 1><<<dim3(4, 8, 32), 256, 0, stream>>>(
        scores, NN, sstr, vT, NN, vstr,
        y, ND, ystr, NN, 1.0f, sizes, nullptr);

    // LN2: y -> ln2o (qk hi region, dead)
    ln_kernel<f16><<<NB * NN, 256, 0, stream>>>(y, g2, ln2o);

    // FC + exact GELU: ln2o -> gelub (vT region, dead)
    gemm_bt<2, 0, 0><<<dim3(4, 256, 1), 256, 0, stream>>>(
        ln2o, 512, 0, wfcT, 512, 0, gelub, 512, 0, 512, 1.0f, nullptr, nullptr);

    // proj -> out (fp32, overwrites all of d_out; scores dead)
    gemm_bt<1, 0, 0><<<dim3(4, 256, 1), 256, 0, stream>>>(
        gelub, 512, 0, wprojT, 512, 0, out, 512, 0, 512, 1.0f, nullptr, nullptr);
}

// Round 2
// 392.341 us; speedup vs baseline: 1.1182x; 1.0425x over previous
//
#include <hip/hip_runtime.h>
#include <hip/hip_bf16.h>
#include <cmath>

// ---------------------------------------------------------------------------
// BeliefTransformerBlock: LN1 -> QKV -> masked attention -> LN2 -> FC+GELU -> proj
// B=32, N=1024, D=512.
//
// R2: dense GEMMs (QKV/FC/proj, K=512) ported to a 256^2-tile 8-wave BK=32
// pipelined kernel (gemm256): 4-slot LDS ring (128 KiB), counted vmcnt(8)
// (never a vmcnt(0) drain in the main loop), ONE barrier per K-step,
// 3-K-tile prefetch depth, setprio(1) around the MFMA cluster (T5).
// Race-freedom: stage for tile t+3 targets the slot whose reads finished
// before THIS iteration's barrier; tile-t readiness = per-wave vmcnt(8)
// (leaves only tiles t+1,t+2 in flight) + barrier extends to all waves.
// Masked attention GEMMs (scores/attnV) stay on the proven 128^2 kernel.
//
// d_ws layout (floor 100 MiB):
//   0  wqkvT/wfcT/wprojT (4 MiB)
//   4  qk [b][n][1024] q|k (64 MiB)   -> after scores: y @4 (32), ln2o @36 (32)
//   68 vT [b][d][n] (32 MiB)          -> after attnV: gelub @68 (32)
// d_out (64 MiB): h/scoresAll scratch, finally fp32 out.
// ---------------------------------------------------------------------------

using f16 = _Float16;
typedef _Float16 f16x8 __attribute__((ext_vector_type(8)));
typedef _Float16 f16x4 __attribute__((ext_vector_type(4)));
typedef _Float16 f16x2 __attribute__((ext_vector_type(2)));
typedef float f32x4 __attribute__((ext_vector_type(4)));

#define NB 32
#define NN 1024
#define ND 512

#define GLOAD_LDS16(g, l)                                                     \
    __builtin_amdgcn_global_load_lds(                                         \
        (const __attribute__((address_space(1))) void*)(g),                   \
        (__attribute__((address_space(3))) void*)(l), 16, 0, 0)

// ---------------------------------------------------------------------------
// All three weights cast + transposed in ONE launch. z: 0=qkv 1=fc 2=proj.
// ---------------------------------------------------------------------------
__global__ void transpose_cast_all(const float* __restrict__ wqkv, f16* __restrict__ wqkvT,
                                   const float* __restrict__ wfc, f16* __restrict__ wfcT,
                                   const float* __restrict__ wproj, f16* __restrict__ wprojT) {
    const int z = blockIdx.z;
    const float* w = (z == 0) ? wqkv : (z == 1) ? wfc : wproj;
    f16* wT       = (z == 0) ? wqkvT : (z == 1) ? wfcT : wprojT;
    const int Ncols = (z == 0) ? 1536 : 512;
    if ((int)blockIdx.x * 32 >= Ncols) return;

    __shared__ float tile[32][33];
    const int n0 = blockIdx.x * 32, k0 = blockIdx.y * 32;
    const int tx = threadIdx.x, ty = threadIdx.y;
    for (int i = ty; i < 32; i += 8)
        tile[i][tx] = w[(long long)(k0 + i) * Ncols + n0 + tx];
    __syncthreads();
    for (int i = ty; i < 32; i += 8)
        wT[(long long)(n0 + i) * 512 + k0 + tx] = (f16)tile[tx][i];
}

// ---------------------------------------------------------------------------
// LayerNorm over last dim (512), no bias. Output fp16. One block per row.
// ---------------------------------------------------------------------------
template <typename TIN>
__global__ __launch_bounds__(256) void ln_kernel(const TIN* __restrict__ x,
                                                 const float* __restrict__ gamma,
                                                 f16* __restrict__ out) {
    const int tid = threadIdx.x;
    const long long base = (long long)blockIdx.x * ND;
    float v0, v1;
    if constexpr (sizeof(TIN) == 4) {
        const float2 t = ((const float2*)(x + base))[tid];
        v0 = t.x; v1 = t.y;
    } else {
        const f16x2 t = ((const f16x2*)(x + base))[tid];
        v0 = (float)t.x; v1 = (float)t.y;
    }

    __shared__ float red[8];
    const int wave = tid >> 6, lane = tid & 63;

    float s = v0 + v1;
#pragma unroll
    for (int o = 32; o > 0; o >>= 1) s += __shfl_down(s, o, 64);
    if (lane == 0) red[wave] = s;
    __syncthreads();
    const float mean = (red[0] + red[1] + red[2] + red[3]) * (1.f / 512.f);
    __syncthreads();

    const float d0 = v0 - mean, d1 = v1 - mean;
    float q = d0 * d0 + d1 * d1;
#pragma unroll
    for (int o = 32; o > 0; o >>= 1) q += __shfl_down(q, o, 64);
    if (lane == 0) red[wave] = q;
    __syncthreads();
    const float var = (red[0] + red[1] + red[2] + red[3]) * (1.f / 512.f);
    const float rstd = rsqrtf(var + 1e-5f);

    f16x2 o2;
    o2.x = (f16)(d0 * rstd * gamma[2 * tid]);
    o2.y = (f16)(d1 * rstd * gamma[2 * tid + 1]);
    ((f16x2*)(out + base))[tid] = o2;
}

// ---------------------------------------------------------------------------
// Masked softmax, fp16 in-place, one WAVE per row (no LDS, no barriers).
// Loads AND stores only c < round64(sz) (attn@V's BK=64 K bound; zero tail).
// ---------------------------------------------------------------------------
__global__ __launch_bounds__(256) void softmax_wave(f16* __restrict__ scores,
                                                    const int* __restrict__ sizes) {
    const int b = blockIdx.y;
    const int wave = threadIdx.x >> 6, lane = threadIdx.x & 63;
    const int row = blockIdx.x * 4 + wave;
    f16* srow = scores + ((long long)b * NN + row) * NN;
    const int sz = sizes[b];
    const int keff = (sz + 63) & ~63;
    const int cbase = lane * 16;

    float v[16];
    if (cbase < keff) {
        const f16x8 a0 = *(const f16x8*)&srow[cbase];
        const f16x8 a1 = *(const f16x8*)&srow[cbase + 8];
#pragma unroll
        for (int e = 0; e < 8; e++) { v[e] = (float)a0[e]; v[8 + e] = (float)a1[e]; }
    } else {
#pragma unroll
        for (int e = 0; e < 16; e++) v[e] = 0.f;
    }

    float m = -1e30f;
#pragma unroll
    for (int e = 0; e < 16; e++)
        if (cbase + e < sz) m = fmaxf(m, v[e]);
#pragma unroll
    for (int o = 32; o > 0; o >>= 1) m = fmaxf(m, __shfl_xor(m, o, 64));

    float s = 0.f;
#pragma unroll
    for (int e = 0; e < 16; e++) {
        v[e] = (cbase + e < sz) ? __expf(v[e] - m) : 0.f;
        s += v[e];
    }
#pragma unroll
    for (int o = 32; o > 0; o >>= 1) s += __shfl_xor(s, o, 64);
    const float inv = 1.f / s;

    if (cbase < keff) {
        f16x8 o0, o1;
#pragma unroll
        for (int e = 0; e < 8; e++) {
            o0[e] = (f16)(v[e] * inv);
            o1[e] = (f16)(v[8 + e] * inv);
        }
        *(f16x8*)&srow[cbase] = o0;
        *(f16x8*)&srow[cbase + 8] = o1;
    }
}

__device__ __forceinline__ float gelu_exact(float x) {
    return 0.5f * x * (1.f + erff(x * 0.70710678118654752f));
}

// ---------------------------------------------------------------------------
// gemm256: dense C[M][N] = A[M][K=512] * Bt[N][K]^T, 256x256 tile, 8 waves
// (2Mx4N, wave-tile 128x64), BK=32, 16 K-tiles, 4-slot LDS ring (128 KiB
// dynamic), counted vmcnt(8) pipeline (3 tiles in flight), one barrier per
// K-step, setprio around MFMA. XCD-swizzled block ids (nwg % 8 == 0).
// LDS bank swizzle: granule g' = g ^ ((row>>1)&3) -> uniform 32 B/bank on
// ds_read_b128; gload_lds dest linear, SOURCE col pre-swizzled (involution).
// MODE 1: fp32 out. 2: GELU f16. 3: QKV split (qk cols <1024, vT^T cols >=1024).
// ---------------------------------------------------------------------------
#define STAGE256(t)                                                           \
    { f16* sl = lds + ((t) & 3) * 16384;                                      \
      GLOAD_LDS16(Ap[0] + (t) * 32, sl + tid * 8);                            \
      GLOAD_LDS16(Ap[1] + (t) * 32, sl + (tid + 512) * 8);                    \
      GLOAD_LDS16(Bp[0] + (t) * 32, sl + 8192 + tid * 8);                     \
      GLOAD_LDS16(Bp[1] + (t) * 32, sl + 8192 + (tid + 512) * 8); }

#define COMPUTE256(t)                                                         \
    { const f16* As_ = lds + ((t) & 3) * 16384;                               \
      const f16* Bs_ = As_ + 8192;                                            \
      f16x8 af[8], bf[4];                                                     \
      _Pragma("unroll") for (int i = 0; i < 8; i++)                           \
          af[i] = *(const f16x8*)&As_[(wr + i * 16 + lrow) * 32 + gq];        \
      _Pragma("unroll") for (int j = 0; j < 4; j++)                           \
          bf[j] = *(const f16x8*)&Bs_[(wc + j * 16 + lrow) * 32 + gq];        \
      __builtin_amdgcn_s_setprio(1);                                          \
      _Pragma("unroll") for (int i = 0; i < 8; i++)                           \
      _Pragma("unroll") for (int j = 0; j < 4; j++)                           \
          acc[i][j] = __builtin_amdgcn_mfma_f32_16x16x32_f16(af[i], bf[j], acc[i][j], 0, 0, 0); \
      __builtin_amdgcn_s_setprio(0); }

#define SYNC256(n)                                                            \
    __builtin_amdgcn_sched_barrier(0);                                        \
    asm volatile("s_waitcnt vmcnt(" #n ")" ::: "memory");                     \
    __builtin_amdgcn_s_barrier();                                             \
    asm volatile("" ::: "memory");

template <int MODE>
__global__ __launch_bounds__(512, 2) void gemm256(
    const f16* __restrict__ A, int lda,
    const f16* __restrict__ Bt, int ldb,
    void* __restrict__ Cv, int ldc, void* __restrict__ Cv2) {
    extern __shared__ __align__(16) f16 lds[];

    const int tid = threadIdx.x;
    const int wave = tid >> 6, lane = tid & 63;
    const int wr = (wave >> 2) * 128, wc = (wave & 3) * 64;
    const int lrow = lane & 15, quad = lane >> 4;
    const int gq = (quad ^ ((lrow >> 1) & 3)) * 8;

    // XCD swizzle (nwg % 8 == 0 for all users: 768, 256)
    const int gx = gridDim.x;
    const int nwg = gx * (int)gridDim.y;
    const int id = blockIdx.y * gx + blockIdx.x;
    const int wid = (id & 7) * (nwg >> 3) + (id >> 3);
    const int m0 = (wid / gx) * 256;
    const int n0 = (wid % gx) * 256;

    f32x4 acc[8][4];
#pragma unroll
    for (int i = 0; i < 8; i++)
#pragma unroll
        for (int j = 0; j < 4; j++) acc[i][j] = (f32x4){0.f, 0.f, 0.f, 0.f};

    // staging sources: 2 passes per matrix; slot s -> row=s>>2, granule g=s&3,
    // source col granule = g ^ ((row>>1)&3)  (involution; LDS dest stays linear)
    const f16* Ap[2];
    const f16* Bp[2];
#pragma unroll
    for (int p = 0; p < 2; p++) {
        const int s = tid + p * 512;
        const int r = s >> 2, g = s & 3;
        const int c = (g ^ ((r >> 1) & 3)) * 8;
        Ap[p] = A + (long long)(m0 + r) * lda + c;
        Bp[p] = Bt + (long long)(n0 + r) * ldb + c;
    }

    // prologue: 3 K-tiles in flight
    STAGE256(0); STAGE256(1); STAGE256(2);

    // main: tile t ready after vmcnt(8)+barrier; stage t+3 into slot freed
    // at the barrier (its reads finished in iter t-1, before this barrier).
    for (int t = 0; t < 13; ++t) {
        SYNC256(8);
        STAGE256(t + 3);
        COMPUTE256(t);
    }
    SYNC256(8);
    COMPUTE256(13);
    SYNC256(4);
    COMPUTE256(14);
    SYNC256(0);
    COMPUTE256(15);

    // epilogue: C/D layout col=lane&15, row=quad*4+reg
    const int cbase = n0 + wc + lrow;
    if constexpr (MODE == 3) {
        if (n0 >= 1024) {
            // V columns: store transposed into vT[b][d][n] as packed f16x4
            f16* vTp = (f16*)Cv2;
#pragma unroll
            for (int i = 0; i < 8; i++) {
                const int rbase = m0 + wr + i * 16 + quad * 4;
                const int bb = rbase >> 10, nrow = rbase & 1023;
                f16* vb = vTp + (long long)bb * (ND * NN) + nrow;
#pragma unroll
                for (int j = 0; j < 4; j++) {
                    const int col = cbase + j * 16 - 1024;
                    f16x4 pk;
#pragma unroll
                    for (int r = 0; r < 4; r++) pk[r] = (f16)acc[i][j][r];
                    *(f16x4*)&vb[(long long)col * NN] = pk;
                }
            }
            return;
        }
        f16* Ch = (f16*)Cv;
#pragma unroll
        for (int i = 0; i < 8; i++) {
            const int rbase = m0 + wr + i * 16 + quad * 4;
#pragma unroll
            for (int j = 0; j < 4; j++) {
                const int col = cbase + j * 16;
#pragma unroll
                for (int r = 0; r < 4; r++)
                    Ch[(long long)(rbase + r) * ldc + col] = (f16)acc[i][j][r];
            }
        }
        return;
    }
    if constexpr (MODE == 1) {
        float* Cf = (float*)Cv;
#pragma unroll
        for (int i = 0; i < 8; i++) {
            const int rbase = m0 + wr + i * 16 + quad * 4;
#pragma unroll
            for (int j = 0; j < 4; j++) {
                const int col = cbase + j * 16;
#pragma unroll
                for (int r = 0; r < 4; r++)
                    Cf[(long long)(rbase + r) * ldc + col] = acc[i][j][r];
            }
        }
    } else {  // MODE 2: GELU -> f16
        f16* Ch = (f16*)Cv;
#pragma unroll
        for (int i = 0; i < 8; i++) {
            const int rbase = m0 + wr + i * 16 + quad * 4;
#pragma unroll
            for (int j = 0; j < 4; j++) {
                const int col = cbase + j * 16;
#pragma unroll
                for (int r = 0; r < 4; r++)
                    Ch[(long long)(rbase + r) * ldc + col] = (f16)gelu_exact(acc[i][j][r]);
            }
        }
    }
}

// ---------------------------------------------------------------------------
// GEMM (128^2, 4 waves, BK=64): kept for the masked attention GEMMs.
// MODE 0: fp16*alpha. MASKN: skip block if n0 >= sizes[z]. MASKK: K bounded.
// ---------------------------------------------------------------------------
template <int MODE, int MASKN, int MASKK>
__global__ __launch_bounds__(256) void gemm_bt(
    const f16* __restrict__ A, int lda, long long strideA,
    const f16* __restrict__ Bt, int ldb, long long strideB,
    void* __restrict__ Cv, int ldc, long long strideC,
    int K, float alpha, const int* __restrict__ sizes, void* __restrict__ Cv2) {
    __shared__ __align__(16) f16 As[128 * 64];
    __shared__ __align__(16) f16 Bs[128 * 64];

    const int tid = threadIdx.x;
    const int wave = tid >> 6, lane = tid & 63;
    const int wr = (wave >> 1) * 64, wc = (wave & 1) * 64;
    const int lrow = lane & 15, quad = lane >> 4;
    const long long m0 = (long long)blockIdx.y * 128;
    const long long n0 = (long long)blockIdx.x * 128;

    if (MASKN) {
        if (n0 >= sizes[blockIdx.z]) return;
    }
    int Keff = K;
    if (MASKK) {
        const int ke = (sizes[blockIdx.z] + 63) & ~63;
        if (ke < Keff) Keff = ke;
    }

    A += (long long)blockIdx.z * strideA;
    Bt += (long long)blockIdx.z * strideB;

    f32x4 acc[4][4];
#pragma unroll
    for (int i = 0; i < 4; i++)
#pragma unroll
        for (int j = 0; j < 4; j++) acc[i][j] = (f32x4){0.f, 0.f, 0.f, 0.f};

    const f16* Ap[4];
    const f16* Bp[4];
#pragma unroll
    for (int p = 0; p < 4; p++) {
        const int s = tid + p * 256;
        const int r = s >> 3, c = ((s & 7) ^ (r & 7)) * 8;
        Ap[p] = A + (m0 + r) * lda + c;
        Bp[p] = Bt + (n0 + r) * ldb + c;
    }

    for (int k0 = 0; k0 < Keff; k0 += 64) {
        __syncthreads();
#pragma unroll
        for (int p = 0; p < 4; p++) GLOAD_LDS16(Ap[p] + k0, &As[(tid + p * 256) * 8]);
#pragma unroll
        for (int p = 0; p < 4; p++) GLOAD_LDS16(Bp[p] + k0, &Bs[(tid + p * 256) * 8]);
        __syncthreads();

#pragma unroll
        for (int h = 0; h < 2; h++) {
            const int gq = ((h * 4 + quad) ^ (lrow & 7)) * 8;
            f16x8 af[4], bf[4];
#pragma unroll
            for (int i = 0; i < 4; i++)
                af[i] = *(const f16x8*)&As[(wr + i * 16 + lrow) * 64 + gq];
#pragma unroll
            for (int j = 0; j < 4; j++)
                bf[j] = *(const f16x8*)&Bs[(wc + j * 16 + lrow) * 64 + gq];
#pragma unroll
            for (int i = 0; i < 4; i++)
#pragma unroll
                for (int j = 0; j < 4; j++)
                    acc[i][j] = __builtin_amdgcn_mfma_f32_16x16x32_f16(af[i], bf[j], acc[i][j], 0, 0, 0);
        }
    }

    f16* Ch = (f16*)Cv + (long long)blockIdx.z * strideC;
#pragma unroll
    for (int i = 0; i < 4; i++) {
        const long long rbase = m0 + wr + i * 16 + quad * 4;
#pragma unroll
        for (int j = 0; j < 4; j++) {
            const long long col = n0 + wc + j * 16 + lrow;
#pragma unroll
            for (int r = 0; r < 4; r++)
                Ch[(rbase + r) * ldc + col] = (f16)(acc[i][j][r] * alpha);
        }
    }
}

// ---------------------------------------------------------------------------
// Launch
// ---------------------------------------------------------------------------
extern "C" void kernel_launch(void* const* d_in, const int* in_sizes, int n_in,
                              void* d_out, int out_size, void* d_ws, size_t ws_size,
                              hipStream_t stream) {
    const float* x     = (const float*)d_in[0];
    const int*   sizes = (const int*)d_in[1];
    const float* g1    = (const float*)d_in[2];
    const float* wqkv  = (const float*)d_in[3];
    const float* g2    = (const float*)d_in[4];
    const float* wfc   = (const float*)d_in[5];
    const float* wproj = (const float*)d_in[6];
    float* out = (float*)d_out;
    char* ws = (char*)d_ws;

    // ---- d_ws layout (floor: 100 MiB, proven available) ----
    f16* wqkvT  = (f16*)(ws + (0ull << 20));    // 1.5 MiB  [1536][512]
    f16* wfcT   = (f16*)(ws + (2ull << 20));    // 0.5 MiB
    f16* wprojT = (f16*)(ws + (3ull << 20));    // 0.5 MiB
    f16* qk     = (f16*)(ws + (4ull << 20));    // 64 MiB [b][n][1024] (q|k)
    f16* vT     = (f16*)(ws + (68ull << 20));   // 32 MiB [b][d][n]
    f16* y      = (f16*)(ws + (4ull << 20));    // 32 MiB (qk lo, dead after scores)
    f16* ln2o   = (f16*)(ws + (36ull << 20));   // 32 MiB (qk hi, dead after scores)
    f16* gelub  = (f16*)(ws + (68ull << 20));   // 32 MiB (vT, dead after attnV)

    // ---- d_out scratch ----
    f16* h      = (f16*)d_out;   // 32 MiB, dead after QKV
    f16* scores = (f16*)d_out;   // 64 MiB (all 32 batches; h dead)

    const long long sstr = (long long)NN * NN;     // score batch stride
    const long long qstr = (long long)NN * 1024;   // qk batch stride
    const long long vstr = (long long)ND * NN;     // vT batch stride
    const long long ystr = (long long)NN * ND;     // y batch stride

    const size_t LDSB = 131072;  // 128 KiB dynamic LDS for gemm256

    // weights -> fp16 transposed (one launch)
    transpose_cast_all<<<dim3(48, 16, 3), dim3(32, 8), 0, stream>>>(
        wqkv, wqkvT, wfc, wfcT, wproj, wprojT);

    // LN1: x -> h
    ln_kernel<float><<<NB * NN, 256, 0, stream>>>(x, g1, h);

    // QKV: q,k -> qk[b][n][1024]; v -> vT[b][d][n] (fused transpose)
    gemm256<3><<<dim3(6, 128), 512, LDSB, stream>>>(
        h, 512, wqkvT, 512, qk, 1024, vT);

    // ---- attention, single phase over all 32 batches ----
    // scores (fp16) = q @ k^T / sqrt(D); skip fully-masked column blocks
    gemm_bt<0, 1, 0><<<dim3(8, 8, 32), 256, 0, stream>>>(
        qk, 1024, qstr, qk + 512, 1024, qstr,
        scores, NN, sstr, 512, 0.044194173824159216f, sizes, nullptr);

    // masked softmax in place (wave per row), zero-fill to round64(sz)
    softmax_wave<<<dim3(NN / 4, NB), 256, 0, stream>>>(scores, sizes);

    // y = attn @ v; K bounded at round64(size)
    gemm_bt<0, 0, 1><<<dim3(4, 8, 32), 256, 0, stream>>>(
        scores, NN, sstr, vT, NN, vstr,
        y, ND, ystr, NN, 1.0f, sizes, nullptr);

    // LN2: y -> ln2o (qk hi region, dead)
    ln_kernel<f16><<<NB * NN, 256, 0, stream>>>(y, g2, ln2o);

    // FC + exact GELU: ln2o -> gelub (vT region, dead)
    gemm256<2><<<dim3(2, 128), 512, LDSB, stream>>>(
        ln2o, 512, wfcT, 512, gelub, 512, nullptr);

    // proj -> out (fp32, overwrites all of d_out; scores dead)
    gemm256<1><<<dim3(2, 128), 512, LDSB, stream>>>(
        gelub, 512, wprojT, 512, out, 512, nullptr);
}